// Round 2
// baseline (248.581 us; speedup 1.0000x reference)
//
#include <hip/hip_runtime.h>
#include <cmath>

#define IMG_H 4096
#define IMG_W 4096
#define TX 64
#define TY 16
#define HALO 5
#define IN_H 26            /* TY + 10 */
#define SW   84            /* staging row stride (words): 84*4=336, 16B-aligned, bank-staggered */
#define SHW  68            /* sh row stride: 68*4=272, 16B-aligned */
#define GRID_X (IMG_W / TX)    /* 64 */
#define GRID_Y (IMG_H / TY)    /* 256 */
#define NPART (GRID_X * GRID_Y) /* 16384 */

struct GW { float w[11]; };

__device__ __forceinline__ int clampi(int v, int lo, int hi) {
  return v < lo ? lo : (v > hi ? hi : v);
}

__global__ __launch_bounds__(256, 3) void ssim_tile_kernel(
    const float* __restrict__ img1, const float* __restrict__ img2,
    float* __restrict__ partial, GW gw) {
  __shared__ __align__(16) float s1[IN_H][SW];
  __shared__ __align__(16) float s2[IN_H][SW];
  __shared__ __align__(16) float sh[5][IN_H][SHW];

  const int tid  = threadIdx.x;
  const int bx = blockIdx.x, by = blockIdx.y;
  const int col0 = bx * TX;
  const int row0 = by * TY;

  // ---- stage rows [row0-5, row0+21), cols [col0-8, col0+72) into s1/s2 ----
  if (bx >= 1 && bx <= GRID_X - 2) {
    // interior-x: vectorized float4 loads (x-range guaranteed in bounds)
    for (int idx = tid; idx < IN_H * 20; idx += 256) {
      int r = idx / 20, q = idx - r * 20;
      int gr = clampi(row0 - HALO + r, 0, IMG_H - 1);
      long base = (long)gr * IMG_W + (col0 - 8 + 4 * q);
      float4 va = *reinterpret_cast<const float4*>(img1 + base);
      float4 vb = *reinterpret_cast<const float4*>(img2 + base);
      *reinterpret_cast<float4*>(&s1[r][4 * q]) = va;
      *reinterpret_cast<float4*>(&s2[r][4 * q]) = vb;
    }
  } else {
    // edge-x blocks (2 of 64 columns): scalar with clamp
    for (int idx = tid; idx < IN_H * 80; idx += 256) {
      int r = idx / 80, j = idx - r * 80;
      int gr = clampi(row0 - HALO + r, 0, IMG_H - 1);
      int gc = clampi(col0 - 8 + j, 0, IMG_W - 1);
      long off = (long)gr * IMG_W + gc;
      s1[r][j] = img1[off];
      s2[r][j] = img2[off];
    }
  }
  __syncthreads();

  // ---- horizontal pass: all 5 channels fused, one LDS read of a,b ----
  if (tid < IN_H * 8) {
    int r = tid >> 3, c0 = (tid & 7) * 8;  // outputs c0..c0+7 need s cols c0..c0+23
    float a[24], b[24];
    #pragma unroll
    for (int m = 0; m < 6; ++m) {
      float4 va = *reinterpret_cast<const float4*>(&s1[r][c0 + 4 * m]);
      float4 vb = *reinterpret_cast<const float4*>(&s2[r][c0 + 4 * m]);
      a[4*m+0] = va.x; a[4*m+1] = va.y; a[4*m+2] = va.z; a[4*m+3] = va.w;
      b[4*m+0] = vb.x; b[4*m+1] = vb.y; b[4*m+2] = vb.z; b[4*m+3] = vb.w;
    }
    float acc[5][8];
    #pragma unroll
    for (int ch = 0; ch < 5; ++ch)
      #pragma unroll
      for (int i = 0; i < 8; ++i) acc[ch][i] = 0.f;
    #pragma unroll
    for (int k = 0; k < 18; ++k) {
      float va = a[k + 3], vb = b[k + 3];
      float vaa = va * va, vbb = vb * vb, vab = va * vb;
      #pragma unroll
      for (int i = 0; i < 8; ++i) {
        int kk = k - i;
        if (kk >= 0 && kk < 11) {
          float w = gw.w[kk];
          acc[0][i] = fmaf(w, va,  acc[0][i]);
          acc[1][i] = fmaf(w, vb,  acc[1][i]);
          acc[2][i] = fmaf(w, vaa, acc[2][i]);
          acc[3][i] = fmaf(w, vbb, acc[3][i]);
          acc[4][i] = fmaf(w, vab, acc[4][i]);
        }
      }
    }
    #pragma unroll
    for (int ch = 0; ch < 5; ++ch) {
      *reinterpret_cast<float4*>(&sh[ch][r][c0]) =
          make_float4(acc[ch][0], acc[ch][1], acc[ch][2], acc[ch][3]);
      *reinterpret_cast<float4*>(&sh[ch][r][c0 + 4]) =
          make_float4(acc[ch][4], acc[ch][5], acc[ch][6], acc[ch][7]);
    }
  }
  __syncthreads();

  // ---- vertical pass (fused 5 ch) + SSIM map, 4 output rows per thread ----
  const int col = tid & 63;
  const int o0  = (tid >> 6) * 4;   // first output row of this strip
  float vacc[5][4];
  #pragma unroll
  for (int ch = 0; ch < 5; ++ch)
    #pragma unroll
    for (int i = 0; i < 4; ++i) vacc[ch][i] = 0.f;
  #pragma unroll
  for (int k = 0; k < 14; ++k) {
    int rr = o0 + k;
    float v0 = sh[0][rr][col];
    float v1 = sh[1][rr][col];
    float v2 = sh[2][rr][col];
    float v3 = sh[3][rr][col];
    float v4 = sh[4][rr][col];
    #pragma unroll
    for (int i = 0; i < 4; ++i) {
      int kk = k - i;
      if (kk >= 0 && kk < 11) {
        float w = gw.w[kk];
        vacc[0][i] = fmaf(w, v0, vacc[0][i]);
        vacc[1][i] = fmaf(w, v1, vacc[1][i]);
        vacc[2][i] = fmaf(w, v2, vacc[2][i]);
        vacc[3][i] = fmaf(w, v3, vacc[3][i]);
        vacc[4][i] = fmaf(w, v4, vacc[4][i]);
      }
    }
  }

  const float C1 = 6.5025f, C2 = 58.5225f;
  float sum = 0.f;
  #pragma unroll
  for (int i = 0; i < 4; ++i) {
    float mu1 = vacc[0][i], mu2 = vacc[1][i];
    float x2  = vacc[2][i], y2 = vacc[3][i], xy = vacc[4][i];
    float mu1s = mu1 * mu1, mu2s = mu2 * mu2, m12 = mu1 * mu2;
    float sg1 = x2 - mu1s, sg2 = y2 - mu2s, sg12 = xy - m12;
    float num = (2.f * m12 + C1) * (2.f * sg12 + C2);
    float den = (mu1s + mu2s + C1) * (sg1 + sg2 + C2);
    sum += num * __builtin_amdgcn_rcpf(den);
  }

  // ---- block reduction ----
  #pragma unroll
  for (int off = 32; off > 0; off >>= 1) sum += __shfl_down(sum, off);
  __shared__ float wsum[4];
  if ((tid & 63) == 0) wsum[tid >> 6] = sum;
  __syncthreads();
  if (tid == 0)
    partial[by * GRID_X + bx] = wsum[0] + wsum[1] + wsum[2] + wsum[3];
}

__global__ __launch_bounds__(1024) void ssim_reduce_kernel(
    const float* __restrict__ partial, float* __restrict__ out) {
  int tid = threadIdx.x;
  double s = 0.0;
  for (int i = tid; i < NPART; i += 1024) s += (double)partial[i];
  #pragma unroll
  for (int off = 32; off > 0; off >>= 1) s += __shfl_down(s, off);
  __shared__ double ws[16];
  if ((tid & 63) == 0) ws[tid >> 6] = s;
  __syncthreads();
  if (tid == 0) {
    double t = 0.0;
    #pragma unroll
    for (int i = 0; i < 16; ++i) t += ws[i];
    out[0] = (float)(t / ((double)IMG_H * (double)IMG_W));
  }
}

extern "C" void kernel_launch(void* const* d_in, const int* in_sizes, int n_in,
                              void* d_out, int out_size, void* d_ws, size_t ws_size,
                              hipStream_t stream) {
  const float* img1 = (const float*)d_in[0];
  const float* img2 = (const float*)d_in[1];
  float* partial = (float*)d_ws;
  float* out = (float*)d_out;

  GW gw;
  double g[11], s = 0.0;
  for (int i = 0; i < 11; ++i) {
    double x = i - 5.0;
    g[i] = exp(-(x * x) / (2.0 * 1.5 * 1.5));
    s += g[i];
  }
  for (int i = 0; i < 11; ++i) gw.w[i] = (float)(g[i] / s);

  dim3 grid(GRID_X, GRID_Y);
  ssim_tile_kernel<<<grid, 256, 0, stream>>>(img1, img2, partial, gw);
  ssim_reduce_kernel<<<1, 1024, 0, stream>>>(partial, out);
}

// Round 3
// 201.503 us; speedup vs baseline: 1.2336x; 1.2336x over previous
//
#include <hip/hip_runtime.h>
#include <cmath>

#define IMG_H 4096
#define IMG_W 4096
#define GX 8
#define GY 64
#define TCOLS 512            /* output cols per block (256 thr x 2) */
#define R 64                 /* output rows per block */
#define NITER (R + 10)       /* 74 h-rows per strip */
#define SWORDS 528           /* staged words per img-row: [c0-8, c0+520) */
#define NF4 132              /* float4 slots per img per row */
#define NSLOT (2*NF4)        /* 264 */

struct GW { float w[11]; };

__device__ __forceinline__ int clampi(int v, int lo, int hi) {
  return v < lo ? lo : (v > hi ? hi : v);
}

__global__ __launch_bounds__(256, 2) void ssim_sweep_kernel(
    const float* __restrict__ img1, const float* __restrict__ img2,
    float* __restrict__ partial, GW gw) {
  __shared__ __align__(16) float sbuf[2][2][SWORDS];

  const int tid  = threadIdx.x;
  const int bx = blockIdx.x, by = blockIdx.y;
  const int c0   = bx * TCOLS;
  const int row0 = by * R;
  const bool edge = (bx == 0) || (bx == GX - 1);

  const int  j0   = tid;                 // staging slot 0..255
  const bool has2 = (tid < NSLOT - 256); // 8 threads take a 2nd slot
  const int  j1   = tid + 256;

  auto load_slot = [&](int j, int gr) -> float4 {
    const float* img = (j < NF4) ? img1 : img2;
    int wo = ((j < NF4) ? j : j - NF4) * 4;
    long rowbase = (long)gr * IMG_W;
    int gc = c0 - 8 + wo;
    if (!edge) {
      return *reinterpret_cast<const float4*>(img + rowbase + gc);
    } else {
      float4 v;
      v.x = img[rowbase + clampi(gc + 0, 0, IMG_W - 1)];
      v.y = img[rowbase + clampi(gc + 1, 0, IMG_W - 1)];
      v.z = img[rowbase + clampi(gc + 2, 0, IMG_W - 1)];
      v.w = img[rowbase + clampi(gc + 3, 0, IMG_W - 1)];
      return v;
    }
  };
  auto store_slot = [&](int buf, int j, float4 v) {
    int im = (j < NF4) ? 0 : 1;
    int wo = ((j < NF4) ? j : j - NF4) * 4;
    *reinterpret_cast<float4*>(&sbuf[buf][im][wo]) = v;
  };

  // ---- prologue: stage h-row 0 into buffer 0 ----
  {
    int gr = clampi(row0 - 5, 0, IMG_H - 1);
    float4 v0 = load_slot(j0, gr);
    store_slot(0, j0, v0);
    if (has2) { float4 v1 = load_slot(j1, gr); store_slot(0, j1, v1); }
  }

  // vertical ring accumulators: 5 channels x 11 slots x 2 cols (registers)
  float acc[5][11][2];
  #pragma unroll
  for (int ch = 0; ch < 5; ++ch)
    #pragma unroll
    for (int s = 0; s < 11; ++s) { acc[ch][s][0] = 0.f; acc[ch][s][1] = 0.f; }

  float sum = 0.f;
  const int base = 2 * tid + 2;   // first staged word of this thread's window

  for (int g = 0; g < 7; ++g) {
    #pragma unroll
    for (int p = 0; p < 11; ++p) {
      const int i = g * 11 + p;
      if (i < NITER) {
        __syncthreads();   // iter i-1 writes of buf[i&1] visible; readers of buf[(i+1)&1] done

        // prefetch next input row (global -> regs), hidden under compute
        float4 pre0, pre1;
        const bool pf = (i + 1 < NITER);
        if (pf) {
          int gr = clampi(row0 - 5 + i + 1, 0, IMG_H - 1);
          pre0 = load_slot(j0, gr);
          if (has2) pre1 = load_slot(j1, gr);
        }

        const int cur = i & 1;
        // window: staged words [2tid+2, 2tid+16)
        float wa[14], wb[14];
        #pragma unroll
        for (int m = 0; m < 7; ++m) {
          float2 fa = *reinterpret_cast<const float2*>(&sbuf[cur][0][base + 2 * m]);
          float2 fb = *reinterpret_cast<const float2*>(&sbuf[cur][1][base + 2 * m]);
          wa[2 * m] = fa.x; wa[2 * m + 1] = fa.y;
          wb[2 * m] = fb.x; wb[2 * m + 1] = fb.y;
        }

        // reset ring slot that starts accumulating a new output this iter
        {
          const int rs = (p + 5) % 11;
          #pragma unroll
          for (int ch = 0; ch < 5; ++ch) { acc[ch][rs][0] = 0.f; acc[ch][rs][1] = 0.f; }
        }

        // fused 5-channel horizontal conv for 2 columns
        float h[5][2];
        #pragma unroll
        for (int ch = 0; ch < 5; ++ch) { h[ch][0] = 0.f; h[ch][1] = 0.f; }
        #pragma unroll
        for (int j = 0; j < 11; ++j) {
          const float wj = gw.w[j];
          float a1 = wa[j + 1], a2 = wa[j + 2];
          float b1 = wb[j + 1], b2 = wb[j + 2];
          h[0][0] = fmaf(wj, a1, h[0][0]);      h[0][1] = fmaf(wj, a2, h[0][1]);
          h[1][0] = fmaf(wj, b1, h[1][0]);      h[1][1] = fmaf(wj, b2, h[1][1]);
          h[2][0] = fmaf(wj, a1 * a1, h[2][0]); h[2][1] = fmaf(wj, a2 * a2, h[2][1]);
          h[3][0] = fmaf(wj, b1 * b1, h[3][0]); h[3][1] = fmaf(wj, b2 * b2, h[3][1]);
          h[4][0] = fmaf(wj, a1 * b1, h[4][0]); h[4][1] = fmaf(wj, a2 * b2, h[4][1]);
        }

        // scatter h-row into the 11 pending output rows (static slots)
        #pragma unroll
        for (int d = -5; d <= 5; ++d) {
          const int s = (p + d + 11) % 11;
          const float wd = gw.w[5 - d];
          #pragma unroll
          for (int ch = 0; ch < 5; ++ch) {
            acc[ch][s][0] = fmaf(wd, h[ch][0], acc[ch][s][0]);
            acc[ch][s][1] = fmaf(wd, h[ch][1], acc[ch][s][1]);
          }
        }

        // output row (i-10) of this strip is complete -> SSIM + sum
        if (i >= 10) {
          const int cs = (p + 6) % 11;
          const float C1 = 6.5025f, C2 = 58.5225f;
          #pragma unroll
          for (int x = 0; x < 2; ++x) {
            float mu1 = acc[0][cs][x], mu2 = acc[1][cs][x];
            float x2 = acc[2][cs][x], y2 = acc[3][cs][x], xy = acc[4][cs][x];
            float mu1s = mu1 * mu1, mu2s = mu2 * mu2, m12 = mu1 * mu2;
            float num = (2.f * m12 + C1) * (2.f * (xy - m12) + C2);
            float den = (mu1s + mu2s + C1) * ((x2 - mu1s) + (y2 - mu2s) + C2);
            sum += num * __builtin_amdgcn_rcpf(den);
          }
        }

        // commit prefetched row to the other buffer
        if (pf) {
          store_slot((i + 1) & 1, j0, pre0);
          if (has2) store_slot((i + 1) & 1, j1, pre1);
        }
      }
    }
  }

  // ---- block reduction ----
  #pragma unroll
  for (int off = 32; off > 0; off >>= 1) sum += __shfl_down(sum, off);
  __shared__ float wsum[4];
  if ((tid & 63) == 0) wsum[tid >> 6] = sum;
  __syncthreads();
  if (tid == 0)
    partial[by * GX + bx] = wsum[0] + wsum[1] + wsum[2] + wsum[3];
}

__global__ __launch_bounds__(256) void ssim_reduce_kernel(
    const float* __restrict__ partial, float* __restrict__ out) {
  const int NPART = GX * GY;  // 512
  int tid = threadIdx.x;
  double s = (double)partial[tid] + (double)partial[tid + 256];
  #pragma unroll
  for (int off = 32; off > 0; off >>= 1) s += __shfl_down(s, off);
  __shared__ double ws[4];
  if ((tid & 63) == 0) ws[tid >> 6] = s;
  __syncthreads();
  if (tid == 0)
    out[0] = (float)((ws[0] + ws[1] + ws[2] + ws[3]) /
                     ((double)IMG_H * (double)IMG_W));
  (void)NPART;
}

extern "C" void kernel_launch(void* const* d_in, const int* in_sizes, int n_in,
                              void* d_out, int out_size, void* d_ws, size_t ws_size,
                              hipStream_t stream) {
  const float* img1 = (const float*)d_in[0];
  const float* img2 = (const float*)d_in[1];
  float* partial = (float*)d_ws;
  float* out = (float*)d_out;

  GW gw;
  double g[11], s = 0.0;
  for (int i = 0; i < 11; ++i) {
    double x = i - 5.0;
    g[i] = exp(-(x * x) / (2.0 * 1.5 * 1.5));
    s += g[i];
  }
  for (int i = 0; i < 11; ++i) gw.w[i] = (float)(g[i] / s);

  dim3 grid(GX, GY);
  ssim_sweep_kernel<<<grid, 256, 0, stream>>>(img1, img2, partial, gw);
  ssim_reduce_kernel<<<1, 256, 0, stream>>>(partial, out);
}